// Round 16
// baseline (99.053 us; speedup 1.0000x reference)
//
#include <hip/hip_runtime.h>
#include <hip/hip_bf16.h>

// F=128, H=128, K=768, T=4, IT=2, S=57
// MEASUREMENT ROUND 2: identical to R14 (74.8us) except k_msgA dispatched 3x
// (idempotent). Delta = 2 x (dur(k_msgA) + gap).

#define NK 768
#define NH 128
#define NCF 98304   // 768*128

typedef float v2f __attribute__((ext_vector_type(2)));

// K1: fused parent + exists + dual GEMMs. grid 384 x 512; block owns rows 2b,2b+1.
__global__ __launch_bounds__(512) void k_pd(const float* __restrict__ pf,
    const float* __restrict__ Wp, const float* __restrict__ bp,
    const float* __restrict__ Wexi, const float* __restrict__ bexi,
    const float* __restrict__ Wel, const float* __restrict__ bel,
    const float* __restrict__ Wne, const float* __restrict__ Wee,
    float* __restrict__ cf0g, float* __restrict__ exO,
    float* __restrict__ A_pack, float* __restrict__ BT,
    float* __restrict__ A0, float* __restrict__ B0,
    unsigned int* __restrict__ flag)
{
    __shared__ float s_pf[128];
    __shared__ float s_cf0[2][128];
    __shared__ __align__(16) char s_scr[16384];
    int t = threadIdx.x;
    int b = blockIdx.x;
    int k0 = 2 * b;
    if (t < 128) s_pf[t] = pf[t];
    if (b == 0 && t == 0) *flag = 0u;
    if ((b & 1) == 0) {
        int h = t >> 2, tt = t & 3;
        A_pack[(b >> 1) * 1024 + h * 8 + 4 + tt] = Wee[tt * 128 + h];
    }
    __syncthreads();
    // ---- phase A: cf0 rows k0,k0+1 = relu(pf @ Wp + bp); exists head ----
    {
        float4* s_part = (float4*)s_scr;           // [8][64]
        int c = t & 63, g = t >> 6;                // float4-col, f-group of 16
        const float4* W4 = (const float4*)Wp;      // row stride 24576 float4
        size_t base = (size_t)b * 64 + c;
        float4 acc = make_float4(0.f, 0.f, 0.f, 0.f);
        #pragma unroll
        for (int q = 0; q < 16; ++q) {
            int f = g * 16 + q;
            float4 w = W4[(size_t)f * 24576 + base];
            float p = s_pf[f];
            acc.x = fmaf(p, w.x, acc.x);
            acc.y = fmaf(p, w.y, acc.y);
            acc.z = fmaf(p, w.z, acc.z);
            acc.w = fmaf(p, w.w, acc.w);
        }
        s_part[g * 64 + c] = acc;
        __syncthreads();
        if (t < 64) {
            float4 r = s_part[t];
            #pragma unroll
            for (int g2 = 1; g2 < 8; ++g2) {
                float4 p = s_part[g2 * 64 + t];
                r.x += p.x; r.y += p.y; r.z += p.z; r.w += p.w;
            }
            float4 bi = ((const float4*)bp)[b * 64 + t];
            r.x = fmaxf(r.x + bi.x, 0.f);
            r.y = fmaxf(r.y + bi.y, 0.f);
            r.z = fmaxf(r.z + bi.z, 0.f);
            r.w = fmaxf(r.w + bi.w, 0.f);
            int row = t >> 5, h4 = t & 31;
            *(float4*)&s_cf0[row][h4 * 4] = r;
            ((float4*)cf0g)[(size_t)b * 64 + t] = r;
            float4 w = ((const float4*)Wexi)[h4];
            float dot = r.x * w.x + r.y * w.y + r.z * w.z + r.w * w.w;
            dot += __shfl_xor(dot, 16);
            dot += __shfl_xor(dot, 8);
            dot += __shfl_xor(dot, 4);
            dot += __shfl_xor(dot, 2);
            dot += __shfl_xor(dot, 1);
            if (h4 == 0) exO[k0 + row] = dot + bexi[0];
        }
    }
    __syncthreads();
    // ---- phase B: 4 GEMMs (Ael->A_pack(+bel), Bel->BT, A0, B0) ----
    {
        float4* s_p2 = (float4*)s_scr;             // [4 mat][4 q][2 row][32 c]
        int mat = t >> 7, q = (t >> 5) & 3, c = t & 31;
        const float* W = (mat == 0) ? Wel : (mat == 1) ? (Wel + 16384)
                       : (mat == 2) ? Wne : (Wne + 16384);
        float4 a0 = make_float4(0.f, 0.f, 0.f, 0.f);
        float4 a1 = make_float4(0.f, 0.f, 0.f, 0.f);
        #pragma unroll 8
        for (int x = q * 32; x < q * 32 + 32; ++x) {
            float4 w = *(const float4*)&W[x * 128 + c * 4];
            float c0 = s_cf0[0][x], c1 = s_cf0[1][x];
            a0.x = fmaf(c0, w.x, a0.x); a0.y = fmaf(c0, w.y, a0.y);
            a0.z = fmaf(c0, w.z, a0.z); a0.w = fmaf(c0, w.w, a0.w);
            a1.x = fmaf(c1, w.x, a1.x); a1.y = fmaf(c1, w.y, a1.y);
            a1.z = fmaf(c1, w.z, a1.z); a1.w = fmaf(c1, w.w, a1.w);
        }
        s_p2[((mat * 4 + q) * 2 + 0) * 32 + c] = a0;
        s_p2[((mat * 4 + q) * 2 + 1) * 32 + c] = a1;
        __syncthreads();
        if (t < 256) {
            int m2 = t >> 6, row = (t >> 5) & 1, c2 = t & 31;
            float4 r = s_p2[((m2 * 4 + 0) * 2 + row) * 32 + c2];
            #pragma unroll
            for (int q2 = 1; q2 < 4; ++q2) {
                float4 p = s_p2[((m2 * 4 + q2) * 2 + row) * 32 + c2];
                r.x += p.x; r.y += p.y; r.z += p.z; r.w += p.w;
            }
            if (m2 == 0) {
                float4 bl = *(const float4*)&bel[c2 * 4];
                float* ap = A_pack + (k0 >> 2) * 1024 + (k0 & 2) + row;
                ap[(c2 * 4 + 0) * 8] = r.x + bl.x;
                ap[(c2 * 4 + 1) * 8] = r.y + bl.y;
                ap[(c2 * 4 + 2) * 8] = r.z + bl.z;
                ap[(c2 * 4 + 3) * 8] = r.w + bl.w;
            } else if (m2 == 1) {
                BT[(c2 * 4 + 0) * NK + k0 + row] = r.x;
                BT[(c2 * 4 + 1) * NK + k0 + row] = r.y;
                BT[(c2 * 4 + 2) * NK + k0 + row] = r.z;
                BT[(c2 * 4 + 3) * NK + k0 + row] = r.w;
            } else if (m2 == 2) {
                ((float4*)A0)[(size_t)(k0 + row) * 32 + c2] = r;
            } else {
                ((float4*)B0)[(size_t)(k0 + row) * 32 + c2] = r;
            }
        }
    }
}

// K2: edge logits + emask + any_edge. grid(192,3) x 256, tile 4i x 256j.
// No LDS staging: bv via coalesced L2 loads; A/W via uniform scalar loads.
__global__ __launch_bounds__(256) void k_edge(const float* __restrict__ A_pack,
    const float* __restrict__ BT, const float* __restrict__ bex,
    const float* __restrict__ exO, float* __restrict__ edge_out,
    unsigned char* __restrict__ mask, unsigned int* __restrict__ flag)
{
    __shared__ float s_exi[4];
    __shared__ unsigned int s_any;
    int t = threadIdx.x;
    int i0 = blockIdx.x * 4;
    int j = blockIdx.y * 256 + t;
    float exj = exO[j];                 // issue early
    if (t < 4) s_exi[t] = exO[i0 + t];
    if (t == 0) s_any = 0u;
    __syncthreads();
    const float* ap = A_pack + blockIdx.x * 1024;   // [128][8], wave-uniform
    const float* btj = BT + j;
    v2f l01[4] = {}, l23[4] = {};
    #pragma unroll 16
    for (int h = 0; h < 128; ++h) {
        float bb = btj[(size_t)h * NK];             // coalesced, L2-resident
        const float* a8 = ap + h * 8;
        float4 av = *(const float4*)a8;             // uniform -> s_load
        float4 wv = *(const float4*)(a8 + 4);       // uniform -> s_load
        v2f e01 = __builtin_elementwise_max((v2f){av.x + bb, av.y + bb}, (v2f){0.f, 0.f});
        v2f e23 = __builtin_elementwise_max((v2f){av.z + bb, av.w + bb}, (v2f){0.f, 0.f});
        l01[0] += e01 * wv.x; l01[1] += e01 * wv.y;
        l01[2] += e01 * wv.z; l01[3] += e01 * wv.w;
        l23[0] += e23 * wv.x; l23[1] += e23 * wv.y;
        l23[2] += e23 * wv.z; l23[3] += e23 * wv.w;
    }
    float b0 = bex[0], b1 = bex[1], b2 = bex[2], b3 = bex[3];
    bool ej = exj > 0.f;
    float4 v0 = make_float4(l01[0].x + b0, l01[1].x + b1, l01[2].x + b2, l01[3].x + b3);
    float4 v1 = make_float4(l01[0].y + b0, l01[1].y + b1, l01[2].y + b2, l01[3].y + b3);
    float4 v2 = make_float4(l23[0].x + b0, l23[1].x + b1, l23[2].x + b2, l23[3].x + b3);
    float4 v3 = make_float4(l23[0].y + b0, l23[1].y + b1, l23[2].y + b2, l23[3].y + b3);
    ((float4*)edge_out)[(size_t)(i0 + 0) * NK + j] = v0;
    ((float4*)edge_out)[(size_t)(i0 + 1) * NK + j] = v1;
    ((float4*)edge_out)[(size_t)(i0 + 2) * NK + j] = v2;
    ((float4*)edge_out)[(size_t)(i0 + 3) * NK + j] = v3;
    bool m0 = ((v0.x > 0.f) | (v0.y > 0.f) | (v0.z > 0.f) | (v0.w > 0.f)) && ej && (s_exi[0] > 0.f);
    bool m1 = ((v1.x > 0.f) | (v1.y > 0.f) | (v1.z > 0.f) | (v1.w > 0.f)) && ej && (s_exi[1] > 0.f);
    bool m2 = ((v2.x > 0.f) | (v2.y > 0.f) | (v2.z > 0.f) | (v2.w > 0.f)) && ej && (s_exi[2] > 0.f);
    bool m3 = ((v3.x > 0.f) | (v3.y > 0.f) | (v3.z > 0.f) | (v3.w > 0.f)) && ej && (s_exi[3] > 0.f);
    mask[(i0 + 0) * NK + j] = m0 ? (unsigned char)1 : (unsigned char)0;
    mask[(i0 + 1) * NK + j] = m1 ? (unsigned char)1 : (unsigned char)0;
    mask[(i0 + 2) * NK + j] = m2 ? (unsigned char)1 : (unsigned char)0;
    mask[(i0 + 3) * NK + j] = m3 ? (unsigned char)1 : (unsigned char)0;
    unsigned long long bal = __ballot((m0 | m1 | m2 | m3) ? 1 : 0);
    if ((t & 63) == 0 && bal) s_any = 1u;
    __syncthreads();
    if (t == 0 && s_any) *flag = 1u;    // idempotent plain store
}

// K3: fused masked-max(B0) + combine -> cf1 + GEMM Wne1 -> A1,B1.
// grid 384 x 512; rows 2b,2b+1. float4 scan; s_madd[j][2] (b64 reads).
__global__ __launch_bounds__(512) void k_msgA(const float* __restrict__ B0,
    const unsigned char* __restrict__ mask, const float* __restrict__ A0,
    const float* __restrict__ bne, const float* __restrict__ cf0,
    const unsigned int* __restrict__ flag, float* __restrict__ cf1,
    const float* __restrict__ Wne1, float* __restrict__ A1, float* __restrict__ B1)
{
    __shared__ float s_madd[768][2];
    __shared__ float s_red[2][16][32][4];   // 16 KB
    __shared__ float s_cf[2][128];
    int t = threadIdx.x;
    int k0 = blockIdx.x * 2;
    for (int idx = t; idx < 384; idx += 512) {
        int r = idx >= 192 ? 1 : 0, j4 = idx - r * 192;
        uchar4 mm = ((const uchar4*)&mask[(k0 + r) * NK])[j4];
        s_madd[j4 * 4 + 0][r] = mm.x ? 0.f : -1e30f;
        s_madd[j4 * 4 + 1][r] = mm.y ? 0.f : -1e30f;
        s_madd[j4 * 4 + 2][r] = mm.z ? 0.f : -1e30f;
        s_madd[j4 * 4 + 3][r] = mm.w ? 0.f : -1e30f;
    }
    __syncthreads();
    int h4 = t & 31, q = t >> 5;
    {
        v2f M00 = {-1e30f, -1e30f}, M01 = M00, M10 = M00, M11 = M00;
        const float4* B4 = (const float4*)B0;   // row stride 32 float4
        #pragma unroll 16
        for (int jj = 0; jj < 48; ++jj) {
            int j = q * 48 + jj;
            float4 b = B4[(size_t)j * 32 + h4];
            v2f mm2 = *(const v2f*)&s_madd[j][0];
            float m0 = mm2.x, m1 = mm2.y;
            M00 = __builtin_elementwise_max(M00, (v2f){b.x + m0, b.y + m0});
            M01 = __builtin_elementwise_max(M01, (v2f){b.z + m0, b.w + m0});
            M10 = __builtin_elementwise_max(M10, (v2f){b.x + m1, b.y + m1});
            M11 = __builtin_elementwise_max(M11, (v2f){b.z + m1, b.w + m1});
        }
        *(v2f*)&s_red[0][q][h4][0] = M00;
        *(v2f*)&s_red[0][q][h4][2] = M01;
        *(v2f*)&s_red[1][q][h4][0] = M10;
        *(v2f*)&s_red[1][q][h4][2] = M11;
    }
    __syncthreads();
    unsigned int fl = *flag;
    if (t < 256) {
        int kk = t >> 7, hh = t & 127;
        int hq = hh >> 2, c = hh & 3;
        float M = s_red[kk][0][hq][c];
        #pragma unroll
        for (int qq = 1; qq < 16; ++qq) M = fmaxf(M, s_red[kk][qq][hq][c]);
        int g = (k0 + kk) * 128 + hh;
        float v = fl ? fmaxf(A0[g] + bne[hh] + M, 0.f) : cf0[g];
        s_cf[kk][hh] = v;
        cf1[g] = v;
    }
    __syncthreads();
    int h = t & 127, kk = (t >> 7) & 1, half = t >> 8;
    const float* W = Wne1 + half * 16384;
    const float* c = &s_cf[kk][0];
    float acc = 0.f;
    #pragma unroll 8
    for (int r = 0; r < 128; ++r)
        acc = fmaf(c[r], W[r * 128 + h], acc);
    float* D = half ? B1 : A1;
    D[(k0 + kk) * 128 + h] = acc;
}

// K4: fused masked-max(B1) + combine -> cf2 (local) + final heads. grid 384 x 512.
__global__ __launch_bounds__(512) void k_finalf(const float* __restrict__ B1,
    const unsigned char* __restrict__ mask, const float* __restrict__ cf0,
    const float* __restrict__ cf1, const float* __restrict__ A1,
    const float* __restrict__ bne1, const unsigned int* __restrict__ flag,
    const float* __restrict__ Wc, const float* __restrict__ bc,
    const float* __restrict__ Wsem, const float* __restrict__ bsem,
    const float* __restrict__ W2, const float* __restrict__ b2,
    float* __restrict__ out)
{
    __shared__ float s_madd[768][2];
    __shared__ float s_red[2][16][32][4];   // 16 KB
    __shared__ float s_M[2][128];
    __shared__ float s_f[2][384];
    __shared__ float s_h[2][128];
    __shared__ float s_hp[2][128];
    int t = threadIdx.x;
    int k0 = blockIdx.x * 2;
    for (int idx = t; idx < 384; idx += 512) {
        int r = idx >= 192 ? 1 : 0, j4 = idx - r * 192;
        uchar4 mm = ((const uchar4*)&mask[(k0 + r) * NK])[j4];
        s_madd[j4 * 4 + 0][r] = mm.x ? 0.f : -1e30f;
        s_madd[j4 * 4 + 1][r] = mm.y ? 0.f : -1e30f;
        s_madd[j4 * 4 + 2][r] = mm.z ? 0.f : -1e30f;
        s_madd[j4 * 4 + 3][r] = mm.w ? 0.f : -1e30f;
    }
    __syncthreads();
    int h4 = t & 31, q = t >> 5;
    {
        v2f M00 = {-1e30f, -1e30f}, M01 = M00, M10 = M00, M11 = M00;
        const float4* B4 = (const float4*)B1;   // row stride 32 float4
        #pragma unroll 16
        for (int jj = 0; jj < 48; ++jj) {
            int j = q * 48 + jj;
            float4 b = B4[(size_t)j * 32 + h4];
            v2f mm2 = *(const v2f*)&s_madd[j][0];
            float m0 = mm2.x, m1 = mm2.y;
            M00 = __builtin_elementwise_max(M00, (v2f){b.x + m0, b.y + m0});
            M01 = __builtin_elementwise_max(M01, (v2f){b.z + m0, b.w + m0});
            M10 = __builtin_elementwise_max(M10, (v2f){b.x + m1, b.y + m1});
            M11 = __builtin_elementwise_max(M11, (v2f){b.z + m1, b.w + m1});
        }
        *(v2f*)&s_red[0][q][h4][0] = M00;
        *(v2f*)&s_red[0][q][h4][2] = M01;
        *(v2f*)&s_red[1][q][h4][0] = M10;
        *(v2f*)&s_red[1][q][h4][2] = M11;
    }
    __syncthreads();
    if (t < 256) {
        int kk = t >> 7, hh = t & 127;
        int hq = hh >> 2, c = hh & 3;
        float M = s_red[kk][0][hq][c];
        #pragma unroll
        for (int qq = 1; qq < 16; ++qq) M = fmaxf(M, s_red[kk][qq][hq][c]);
        s_M[kk][hh] = M;
    }
    __syncthreads();
    unsigned int fl = *flag;
    for (int idx = t; idx < 768; idx += 512) {
        int kk = idx >= 384 ? 1 : 0;
        int c = idx - kk * 384;
        int row = k0 + kk;
        float v;
        if (c < 128) v = cf0[row * 128 + c];
        else if (c < 256) v = cf1[row * 128 + (c - 128)];
        else {
            int hh = c - 256, g = row * 128 + hh;
            v = fl ? fmaxf(A1[g] + bne1[hh] + s_M[kk][hh], 0.f) : cf1[g];
        }
        s_f[kk][c] = v;
    }
    __syncthreads();
    int h = t & 127, rh = (t >> 7) & 1, kg = t >> 8;
    float acc = 0.f;
    {
        const float* f = &s_f[kg][rh * 192];
        const float* Wcp = Wc + rh * 192 * 128;
        #pragma unroll 8
        for (int r = 0; r < 192; ++r)
            acc = fmaf(f[r], Wcp[r * 128 + h], acc);
    }
    if (rh) s_hp[kg][h] = acc;
    __syncthreads();
    if (!rh) s_h[kg][h] = fmaxf(acc + s_hp[kg][h] + bc[h], 0.f);
    __syncthreads();
    float a2 = 0.f;
    {
        const float* hr = &s_h[kg][rh * 64];
        const float* W2p = W2 + rh * 64 * 128;
        #pragma unroll 8
        for (int r = 0; r < 64; ++r)
            a2 = fmaf(hr[r], W2p[r * 128 + h], a2);
    }
    if (rh) s_hp[kg][h] = a2;
    __syncthreads();
    if (!rh) out[(size_t)(k0 + kg) * 128 + h] = fmaxf(a2 + s_hp[kg][h] + b2[h], 0.f);
    if (t < 114) {
        int kk = t / 57, sidx = t - kk * 57;
        float ss = bsem[sidx];
        const float* hr = &s_h[kk][0];
        #pragma unroll 8
        for (int r = 0; r < 128; ++r)
            ss = fmaf(hr[r], Wsem[r * 57 + sidx], ss);
        out[98304 + (size_t)(k0 + kk) * 57 + sidx] = ss;
    }
}

extern "C" void kernel_launch(void* const* d_in, const int* in_sizes, int n_in,
                              void* d_out, int out_size, void* d_ws, size_t ws_size,
                              hipStream_t stream) {
    const float* pf   = (const float*)d_in[0];
    const float* Wp   = (const float*)d_in[1];
    const float* bp   = (const float*)d_in[2];
    const float* Wexi = (const float*)d_in[3];
    const float* bexi = (const float*)d_in[4];
    const float* Wel  = (const float*)d_in[5];
    const float* bel  = (const float*)d_in[6];
    const float* Wee  = (const float*)d_in[7];
    const float* bee  = (const float*)d_in[8];
    const float* Wne  = (const float*)d_in[9];
    const float* bne  = (const float*)d_in[10];
    const float* Wc   = (const float*)d_in[11];
    const float* bc   = (const float*)d_in[12];
    const float* Wsem = (const float*)d_in[13];
    const float* bsem = (const float*)d_in[14];
    const float* W2   = (const float*)d_in[15];
    const float* b2   = (const float*)d_in[16];
    float* out = (float*)d_out;
    float* ws  = (float*)d_ws;
    const int N = NCF;
    float* cf0    = ws;
    float* cf1    = ws + N;
    float* A_pack = ws + 2 * N;                            // 192*128*8 = 2N floats
    float* BT     = ws + 4 * N;
    float* A0     = ws + 5 * N;
    float* B0     = ws + 6 * N;
    float* A1     = ws + 7 * N;
    float* B1     = ws + 8 * N;
    unsigned char* mask = (unsigned char*)(ws + 9 * N);    // 589824 bytes
    unsigned int* flag  = (unsigned int*)(mask + 589824);

    float* out_ex   = out + 142080;
    float* out_edge = out + 142848;

    k_pd<<<384, 512, 0, stream>>>(pf, Wp, bp, Wexi, bexi, Wel, bel, Wne, Wee,
                                  cf0, out_ex, A_pack, BT, A0, B0, flag);
    k_edge<<<dim3(192, 3), 256, 0, stream>>>(A_pack, BT, bee, out_ex,
                                             out_edge, mask, flag);
    // k_msgA dispatched 3x (idempotent): dur(k_msgA) = (total - 74.8)/2 - gap
    k_msgA<<<384, 512, 0, stream>>>(B0, mask, A0, bne, cf0, flag, cf1,
                                    Wne + 32768, A1, B1);
    k_msgA<<<384, 512, 0, stream>>>(B0, mask, A0, bne, cf0, flag, cf1,
                                    Wne + 32768, A1, B1);
    k_msgA<<<384, 512, 0, stream>>>(B0, mask, A0, bne, cf0, flag, cf1,
                                    Wne + 32768, A1, B1);
    k_finalf<<<384, 512, 0, stream>>>(B1, mask, cf0, cf1, A1, bne + 128, flag,
                                      Wc, bc, Wsem, bsem, W2, b2, out);
}

// Round 17
// 93.057 us; speedup vs baseline: 1.0644x; 1.0644x over previous
//
#include <hip/hip_runtime.h>
#include <hip/hip_bf16.h>

// F=128, H=128, K=768, T=4, IT=2, S=57
// 4-dispatch pipeline: k_pd -> k_edge -> k_msgA -> k_finalf
// Barrier-minimized: main load streams issue at cycle ~0 in every kernel.

#define NK 768
#define NH 128
#define NCF 98304   // 768*128

typedef float v2f __attribute__((ext_vector_type(2)));

// K1: fused parent + exists + dual GEMMs. grid 384 x 512; block owns rows 2b,2b+1.
__global__ __launch_bounds__(512) void k_pd(const float* __restrict__ pf,
    const float* __restrict__ Wp, const float* __restrict__ bp,
    const float* __restrict__ Wexi, const float* __restrict__ bexi,
    const float* __restrict__ Wel, const float* __restrict__ bel,
    const float* __restrict__ Wne, const float* __restrict__ Wee,
    float* __restrict__ cf0g, float* __restrict__ exO,
    float* __restrict__ A_pack, float* __restrict__ BT,
    float* __restrict__ A0, float* __restrict__ B0,
    unsigned int* __restrict__ flag)
{
    __shared__ float s_cf0[2][128];
    __shared__ __align__(16) char s_scr[16384];
    int t = threadIdx.x;
    int b = blockIdx.x;
    int k0 = 2 * b;
    if (b == 0 && t == 0) *flag = 0u;
    if ((b & 1) == 0) {
        int h = t >> 2, tt = t & 3;
        A_pack[(b >> 1) * 1024 + h * 8 + 4 + tt] = Wee[tt * 128 + h];
    }
    // ---- phase A: cf0 rows k0,k0+1 = relu(pf @ Wp + bp); exists head ----
    // No s_pf staging: pf slice is wave-uniform (g = t>>6) -> broadcast loads;
    // the 16 big W loads issue immediately at kernel start.
    {
        float4* s_part = (float4*)s_scr;           // [8][64]
        int c = t & 63, g = t >> 6;                // float4-col, f-group of 16
        const float4* W4 = (const float4*)Wp;      // row stride 24576 float4
        size_t base = (size_t)b * 64 + c;
        const float4* pf4 = (const float4*)(pf + g * 16);
        float4 p0 = pf4[0], p1 = pf4[1], p2 = pf4[2], p3 = pf4[3];
        float pv[16] = { p0.x, p0.y, p0.z, p0.w, p1.x, p1.y, p1.z, p1.w,
                         p2.x, p2.y, p2.z, p2.w, p3.x, p3.y, p3.z, p3.w };
        float4 acc = make_float4(0.f, 0.f, 0.f, 0.f);
        #pragma unroll
        for (int q = 0; q < 16; ++q) {
            int f = g * 16 + q;
            float4 w = W4[(size_t)f * 24576 + base];
            float p = pv[q];
            acc.x = fmaf(p, w.x, acc.x);
            acc.y = fmaf(p, w.y, acc.y);
            acc.z = fmaf(p, w.z, acc.z);
            acc.w = fmaf(p, w.w, acc.w);
        }
        s_part[g * 64 + c] = acc;
        __syncthreads();
        if (t < 64) {
            float4 r = s_part[t];
            #pragma unroll
            for (int g2 = 1; g2 < 8; ++g2) {
                float4 p = s_part[g2 * 64 + t];
                r.x += p.x; r.y += p.y; r.z += p.z; r.w += p.w;
            }
            float4 bi = ((const float4*)bp)[b * 64 + t];
            r.x = fmaxf(r.x + bi.x, 0.f);
            r.y = fmaxf(r.y + bi.y, 0.f);
            r.z = fmaxf(r.z + bi.z, 0.f);
            r.w = fmaxf(r.w + bi.w, 0.f);
            int row = t >> 5, h4 = t & 31;
            *(float4*)&s_cf0[row][h4 * 4] = r;
            ((float4*)cf0g)[(size_t)b * 64 + t] = r;
            float4 w = ((const float4*)Wexi)[h4];
            float dot = r.x * w.x + r.y * w.y + r.z * w.z + r.w * w.w;
            dot += __shfl_xor(dot, 16);
            dot += __shfl_xor(dot, 8);
            dot += __shfl_xor(dot, 4);
            dot += __shfl_xor(dot, 2);
            dot += __shfl_xor(dot, 1);
            if (h4 == 0) exO[k0 + row] = dot + bexi[0];
        }
    }
    __syncthreads();
    // ---- phase B: 4 GEMMs (Ael->A_pack(+bel), Bel->BT, A0, B0) ----
    {
        float4* s_p2 = (float4*)s_scr;             // [4 mat][4 q][2 row][32 c]
        int mat = t >> 7, q = (t >> 5) & 3, c = t & 31;
        const float* W = (mat == 0) ? Wel : (mat == 1) ? (Wel + 16384)
                       : (mat == 2) ? Wne : (Wne + 16384);
        float4 a0 = make_float4(0.f, 0.f, 0.f, 0.f);
        float4 a1 = make_float4(0.f, 0.f, 0.f, 0.f);
        #pragma unroll 8
        for (int x = q * 32; x < q * 32 + 32; ++x) {
            float4 w = *(const float4*)&W[x * 128 + c * 4];
            float c0 = s_cf0[0][x], c1 = s_cf0[1][x];
            a0.x = fmaf(c0, w.x, a0.x); a0.y = fmaf(c0, w.y, a0.y);
            a0.z = fmaf(c0, w.z, a0.z); a0.w = fmaf(c0, w.w, a0.w);
            a1.x = fmaf(c1, w.x, a1.x); a1.y = fmaf(c1, w.y, a1.y);
            a1.z = fmaf(c1, w.z, a1.z); a1.w = fmaf(c1, w.w, a1.w);
        }
        s_p2[((mat * 4 + q) * 2 + 0) * 32 + c] = a0;
        s_p2[((mat * 4 + q) * 2 + 1) * 32 + c] = a1;
        __syncthreads();
        if (t < 256) {
            int m2 = t >> 6, row = (t >> 5) & 1, c2 = t & 31;
            float4 r = s_p2[((m2 * 4 + 0) * 2 + row) * 32 + c2];
            #pragma unroll
            for (int q2 = 1; q2 < 4; ++q2) {
                float4 p = s_p2[((m2 * 4 + q2) * 2 + row) * 32 + c2];
                r.x += p.x; r.y += p.y; r.z += p.z; r.w += p.w;
            }
            if (m2 == 0) {
                float4 bl = *(const float4*)&bel[c2 * 4];
                float* ap = A_pack + (k0 >> 2) * 1024 + (k0 & 2) + row;
                ap[(c2 * 4 + 0) * 8] = r.x + bl.x;
                ap[(c2 * 4 + 1) * 8] = r.y + bl.y;
                ap[(c2 * 4 + 2) * 8] = r.z + bl.z;
                ap[(c2 * 4 + 3) * 8] = r.w + bl.w;
            } else if (m2 == 1) {
                BT[(c2 * 4 + 0) * NK + k0 + row] = r.x;
                BT[(c2 * 4 + 1) * NK + k0 + row] = r.y;
                BT[(c2 * 4 + 2) * NK + k0 + row] = r.z;
                BT[(c2 * 4 + 3) * NK + k0 + row] = r.w;
            } else if (m2 == 2) {
                ((float4*)A0)[(size_t)(k0 + row) * 32 + c2] = r;
            } else {
                ((float4*)B0)[(size_t)(k0 + row) * 32 + c2] = r;
            }
        }
    }
}

// K2: edge logits + emask + any_edge. grid(192,3) x 256, tile 4i x 256j.
// Barrier-free: no LDS at all; exi via uniform loads; flag via ballot + store.
__global__ __launch_bounds__(256) void k_edge(const float* __restrict__ A_pack,
    const float* __restrict__ BT, const float* __restrict__ bex,
    const float* __restrict__ exO, float* __restrict__ edge_out,
    unsigned char* __restrict__ mask, unsigned int* __restrict__ flag)
{
    int t = threadIdx.x;
    int i0 = blockIdx.x * 4;
    int j = blockIdx.y * 256 + t;
    float exj = exO[j];                 // issue early
    float exi0 = exO[i0 + 0];           // wave-uniform
    float exi1 = exO[i0 + 1];
    float exi2 = exO[i0 + 2];
    float exi3 = exO[i0 + 3];
    const float* ap = A_pack + blockIdx.x * 1024;   // [128][8], wave-uniform
    const float* btj = BT + j;
    v2f l01[4] = {}, l23[4] = {};
    #pragma unroll 16
    for (int h = 0; h < 128; ++h) {
        float bb = btj[(size_t)h * NK];             // coalesced, L2-resident
        const float* a8 = ap + h * 8;
        float4 av = *(const float4*)a8;             // uniform -> s_load
        float4 wv = *(const float4*)(a8 + 4);       // uniform -> s_load
        v2f e01 = __builtin_elementwise_max((v2f){av.x + bb, av.y + bb}, (v2f){0.f, 0.f});
        v2f e23 = __builtin_elementwise_max((v2f){av.z + bb, av.w + bb}, (v2f){0.f, 0.f});
        l01[0] += e01 * wv.x; l01[1] += e01 * wv.y;
        l01[2] += e01 * wv.z; l01[3] += e01 * wv.w;
        l23[0] += e23 * wv.x; l23[1] += e23 * wv.y;
        l23[2] += e23 * wv.z; l23[3] += e23 * wv.w;
    }
    float b0 = bex[0], b1 = bex[1], b2 = bex[2], b3 = bex[3];
    bool ej = exj > 0.f;
    float4 v0 = make_float4(l01[0].x + b0, l01[1].x + b1, l01[2].x + b2, l01[3].x + b3);
    float4 v1 = make_float4(l01[0].y + b0, l01[1].y + b1, l01[2].y + b2, l01[3].y + b3);
    float4 v2 = make_float4(l23[0].x + b0, l23[1].x + b1, l23[2].x + b2, l23[3].x + b3);
    float4 v3 = make_float4(l23[0].y + b0, l23[1].y + b1, l23[2].y + b2, l23[3].y + b3);
    ((float4*)edge_out)[(size_t)(i0 + 0) * NK + j] = v0;
    ((float4*)edge_out)[(size_t)(i0 + 1) * NK + j] = v1;
    ((float4*)edge_out)[(size_t)(i0 + 2) * NK + j] = v2;
    ((float4*)edge_out)[(size_t)(i0 + 3) * NK + j] = v3;
    bool m0 = ((v0.x > 0.f) | (v0.y > 0.f) | (v0.z > 0.f) | (v0.w > 0.f)) && ej && (exi0 > 0.f);
    bool m1 = ((v1.x > 0.f) | (v1.y > 0.f) | (v1.z > 0.f) | (v1.w > 0.f)) && ej && (exi1 > 0.f);
    bool m2 = ((v2.x > 0.f) | (v2.y > 0.f) | (v2.z > 0.f) | (v2.w > 0.f)) && ej && (exi2 > 0.f);
    bool m3 = ((v3.x > 0.f) | (v3.y > 0.f) | (v3.z > 0.f) | (v3.w > 0.f)) && ej && (exi3 > 0.f);
    mask[(i0 + 0) * NK + j] = m0 ? (unsigned char)1 : (unsigned char)0;
    mask[(i0 + 1) * NK + j] = m1 ? (unsigned char)1 : (unsigned char)0;
    mask[(i0 + 2) * NK + j] = m2 ? (unsigned char)1 : (unsigned char)0;
    mask[(i0 + 3) * NK + j] = m3 ? (unsigned char)1 : (unsigned char)0;
    unsigned long long bal = __ballot((m0 | m1 | m2 | m3) ? 1 : 0);
    if ((t & 63) == 0 && bal) *flag = 1u;   // idempotent plain store
}

// K3: fused masked-max(B0) + combine -> cf1 + GEMM Wne1 -> A1,B1.
// grid 384 x 512; rows 2b,2b+1. Direct uchar4 mask loads in scan (no staging).
__global__ __launch_bounds__(512) void k_msgA(const float* __restrict__ B0,
    const unsigned char* __restrict__ mask, const float* __restrict__ A0,
    const float* __restrict__ bne, const float* __restrict__ cf0,
    const unsigned int* __restrict__ flag, float* __restrict__ cf1,
    const float* __restrict__ Wne1, float* __restrict__ A1, float* __restrict__ B1)
{
    __shared__ float s_red[2][16][32][4];   // 16 KB
    __shared__ float s_cf[2][128];
    int t = threadIdx.x;
    int k0 = blockIdx.x * 2;
    int h4 = t & 31, q = t >> 5;
    {
        v2f M00 = {-1e30f, -1e30f}, M01 = M00, M10 = M00, M11 = M00;
        const float4* B4 = (const float4*)B0;   // row stride 32 float4
        const uchar4* m0p = (const uchar4*)(mask + (size_t)k0 * NK) + q * 12;
        const uchar4* m1p = (const uchar4*)(mask + (size_t)(k0 + 1) * NK) + q * 12;
        #pragma unroll 4
        for (int j4 = 0; j4 < 12; ++j4) {
            uchar4 a = m0p[j4];
            uchar4 bq = m1p[j4];
            unsigned char am[4], bm[4];
            *(uchar4*)am = a; *(uchar4*)bm = bq;
            #pragma unroll
            for (int e = 0; e < 4; ++e) {
                int j = q * 48 + j4 * 4 + e;
                float4 b = B4[(size_t)j * 32 + h4];
                float m0 = am[e] ? 0.f : -1e30f;
                float m1 = bm[e] ? 0.f : -1e30f;
                M00 = __builtin_elementwise_max(M00, (v2f){b.x + m0, b.y + m0});
                M01 = __builtin_elementwise_max(M01, (v2f){b.z + m0, b.w + m0});
                M10 = __builtin_elementwise_max(M10, (v2f){b.x + m1, b.y + m1});
                M11 = __builtin_elementwise_max(M11, (v2f){b.z + m1, b.w + m1});
            }
        }
        *(v2f*)&s_red[0][q][h4][0] = M00;
        *(v2f*)&s_red[0][q][h4][2] = M01;
        *(v2f*)&s_red[1][q][h4][0] = M10;
        *(v2f*)&s_red[1][q][h4][2] = M11;
    }
    __syncthreads();
    unsigned int fl = *flag;
    if (t < 256) {
        int kk = t >> 7, hh = t & 127;
        int hq = hh >> 2, c = hh & 3;
        float M = s_red[kk][0][hq][c];
        #pragma unroll
        for (int qq = 1; qq < 16; ++qq) M = fmaxf(M, s_red[kk][qq][hq][c]);
        int g = (k0 + kk) * 128 + hh;
        float v = fl ? fmaxf(A0[g] + bne[hh] + M, 0.f) : cf0[g];
        s_cf[kk][hh] = v;
        cf1[g] = v;
    }
    __syncthreads();
    int h = t & 127, kk = (t >> 7) & 1, half = t >> 8;
    const float* W = Wne1 + half * 16384;
    const float* c = &s_cf[kk][0];
    float acc = 0.f;
    #pragma unroll 8
    for (int r = 0; r < 128; ++r)
        acc = fmaf(c[r], W[r * 128 + h], acc);
    float* D = half ? B1 : A1;
    D[(k0 + kk) * 128 + h] = acc;
}

// K4: fused masked-max(B1) + combine -> cf2 (local) + final heads. grid 384 x 512.
__global__ __launch_bounds__(512) void k_finalf(const float* __restrict__ B1,
    const unsigned char* __restrict__ mask, const float* __restrict__ cf0,
    const float* __restrict__ cf1, const float* __restrict__ A1,
    const float* __restrict__ bne1, const unsigned int* __restrict__ flag,
    const float* __restrict__ Wc, const float* __restrict__ bc,
    const float* __restrict__ Wsem, const float* __restrict__ bsem,
    const float* __restrict__ W2, const float* __restrict__ b2,
    float* __restrict__ out)
{
    __shared__ float s_red[2][16][32][4];   // 16 KB
    __shared__ float s_M[2][128];
    __shared__ float s_f[2][384];
    __shared__ float s_h[2][128];
    __shared__ float s_hp[2][128];
    int t = threadIdx.x;
    int k0 = blockIdx.x * 2;
    int h4 = t & 31, q = t >> 5;
    {
        v2f M00 = {-1e30f, -1e30f}, M01 = M00, M10 = M00, M11 = M00;
        const float4* B4 = (const float4*)B1;   // row stride 32 float4
        const uchar4* m0p = (const uchar4*)(mask + (size_t)k0 * NK) + q * 12;
        const uchar4* m1p = (const uchar4*)(mask + (size_t)(k0 + 1) * NK) + q * 12;
        #pragma unroll 4
        for (int j4 = 0; j4 < 12; ++j4) {
            uchar4 a = m0p[j4];
            uchar4 bq = m1p[j4];
            unsigned char am[4], bm[4];
            *(uchar4*)am = a; *(uchar4*)bm = bq;
            #pragma unroll
            for (int e = 0; e < 4; ++e) {
                int j = q * 48 + j4 * 4 + e;
                float4 b = B4[(size_t)j * 32 + h4];
                float m0 = am[e] ? 0.f : -1e30f;
                float m1 = bm[e] ? 0.f : -1e30f;
                M00 = __builtin_elementwise_max(M00, (v2f){b.x + m0, b.y + m0});
                M01 = __builtin_elementwise_max(M01, (v2f){b.z + m0, b.w + m0});
                M10 = __builtin_elementwise_max(M10, (v2f){b.x + m1, b.y + m1});
                M11 = __builtin_elementwise_max(M11, (v2f){b.z + m1, b.w + m1});
            }
        }
        *(v2f*)&s_red[0][q][h4][0] = M00;
        *(v2f*)&s_red[0][q][h4][2] = M01;
        *(v2f*)&s_red[1][q][h4][0] = M10;
        *(v2f*)&s_red[1][q][h4][2] = M11;
    }
    __syncthreads();
    if (t < 256) {
        int kk = t >> 7, hh = t & 127;
        int hq = hh >> 2, c = hh & 3;
        float M = s_red[kk][0][hq][c];
        #pragma unroll
        for (int qq = 1; qq < 16; ++qq) M = fmaxf(M, s_red[kk][qq][hq][c]);
        s_M[kk][hh] = M;
    }
    __syncthreads();
    unsigned int fl = *flag;
    for (int idx = t; idx < 768; idx += 512) {
        int kk = idx >= 384 ? 1 : 0;
        int c = idx - kk * 384;
        int row = k0 + kk;
        float v;
        if (c < 128) v = cf0[row * 128 + c];
        else if (c < 256) v = cf1[row * 128 + (c - 128)];
        else {
            int hh = c - 256, g = row * 128 + hh;
            v = fl ? fmaxf(A1[g] + bne1[hh] + s_M[kk][hh], 0.f) : cf1[g];
        }
        s_f[kk][c] = v;
    }
    __syncthreads();
    int h = t & 127, rh = (t >> 7) & 1, kg = t >> 8;
    float acc = 0.f;
    {
        const float* f = &s_f[kg][rh * 192];
        const float* Wcp = Wc + rh * 192 * 128;
        #pragma unroll 8
        for (int r = 0; r < 192; ++r)
            acc = fmaf(f[r], Wcp[r * 128 + h], acc);
    }
    if (rh) s_hp[kg][h] = acc;
    __syncthreads();
    if (!rh) s_h[kg][h] = fmaxf(acc + s_hp[kg][h] + bc[h], 0.f);
    __syncthreads();
    float a2 = 0.f;
    {
        const float* hr = &s_h[kg][rh * 64];
        const float* W2p = W2 + rh * 64 * 128;
        #pragma unroll 8
        for (int r = 0; r < 64; ++r)
            a2 = fmaf(hr[r], W2p[r * 128 + h], a2);
    }
    if (rh) s_hp[kg][h] = a2;
    __syncthreads();
    if (!rh) out[(size_t)(k0 + kg) * 128 + h] = fmaxf(a2 + s_hp[kg][h] + b2[h], 0.f);
    if (t < 114) {
        int kk = t / 57, sidx = t - kk * 57;
        float ss = bsem[sidx];
        const float* hr = &s_h[kk][0];
        #pragma unroll 8
        for (int r = 0; r < 128; ++r)
            ss = fmaf(hr[r], Wsem[r * 57 + sidx], ss);
        out[98304 + (size_t)(k0 + kk) * 57 + sidx] = ss;
    }
}

extern "C" void kernel_launch(void* const* d_in, const int* in_sizes, int n_in,
                              void* d_out, int out_size, void* d_ws, size_t ws_size,
                              hipStream_t stream) {
    const float* pf   = (const float*)d_in[0];
    const float* Wp   = (const float*)d_in[1];
    const float* bp   = (const float*)d_in[2];
    const float* Wexi = (const float*)d_in[3];
    const float* bexi = (const float*)d_in[4];
    const float* Wel  = (const float*)d_in[5];
    const float* bel  = (const float*)d_in[6];
    const float* Wee  = (const float*)d_in[7];
    const float* bee  = (const float*)d_in[8];
    const float* Wne  = (const float*)d_in[9];
    const float* bne  = (const float*)d_in[10];
    const float* Wc   = (const float*)d_in[11];
    const float* bc   = (const float*)d_in[12];
    const float* Wsem = (const float*)d_in[13];
    const float* bsem = (const float*)d_in[14];
    const float* W2   = (const float*)d_in[15];
    const float* b2   = (const float*)d_in[16];
    float* out = (float*)d_out;
    float* ws  = (float*)d_ws;
    const int N = NCF;
    float* cf0    = ws;
    float* cf1    = ws + N;
    float* A_pack = ws + 2 * N;                            // 192*128*8 = 2N floats
    float* BT     = ws + 4 * N;
    float* A0     = ws + 5 * N;
    float* B0     = ws + 6 * N;
    float* A1     = ws + 7 * N;
    float* B1     = ws + 8 * N;
    unsigned char* mask = (unsigned char*)(ws + 9 * N);    // 589824 bytes
    unsigned int* flag  = (unsigned int*)(mask + 589824);

    float* out_ex   = out + 142080;
    float* out_edge = out + 142848;

    k_pd<<<384, 512, 0, stream>>>(pf, Wp, bp, Wexi, bexi, Wel, bel, Wne, Wee,
                                  cf0, out_ex, A_pack, BT, A0, B0, flag);
    k_edge<<<dim3(192, 3), 256, 0, stream>>>(A_pack, BT, bee, out_ex,
                                             out_edge, mask, flag);
    k_msgA<<<384, 512, 0, stream>>>(B0, mask, A0, bne, cf0, flag, cf1,
                                    Wne + 32768, A1, B1);
    k_finalf<<<384, 512, 0, stream>>>(B1, mask, cf0, cf1, A1, bne + 128, flag,
                                      Wc, bc, Wsem, bsem, W2, b2, out);
}

// Round 18
// 73.541 us; speedup vs baseline: 1.3469x; 1.2654x over previous
//
#include <hip/hip_runtime.h>
#include <hip/hip_bf16.h>

// F=128, H=128, K=768, T=4, IT=2, S=57
// 4-dispatch pipeline: k_pd -> k_edge -> k_msgA -> k_finalf
// k_pd/k_edge: R16 simplified (barrier-free edge). k_msgA/k_finalf: R14 forms
// (LDS mask staging - R16 proved direct broadcast mask loads are 3x slower).

#define NK 768
#define NH 128
#define NCF 98304   // 768*128

typedef float v2f __attribute__((ext_vector_type(2)));

// K1: fused parent + exists + dual GEMMs. grid 384 x 512; block owns rows 2b,2b+1.
__global__ __launch_bounds__(512) void k_pd(const float* __restrict__ pf,
    const float* __restrict__ Wp, const float* __restrict__ bp,
    const float* __restrict__ Wexi, const float* __restrict__ bexi,
    const float* __restrict__ Wel, const float* __restrict__ bel,
    const float* __restrict__ Wne, const float* __restrict__ Wee,
    float* __restrict__ cf0g, float* __restrict__ exO,
    float* __restrict__ A_pack, float* __restrict__ BT,
    float* __restrict__ A0, float* __restrict__ B0,
    unsigned int* __restrict__ flag)
{
    __shared__ float s_cf0[2][128];
    __shared__ __align__(16) char s_scr[16384];
    int t = threadIdx.x;
    int b = blockIdx.x;
    int k0 = 2 * b;
    if (b == 0 && t == 0) *flag = 0u;
    if ((b & 1) == 0) {
        int h = t >> 2, tt = t & 3;
        A_pack[(b >> 1) * 1024 + h * 8 + 4 + tt] = Wee[tt * 128 + h];
    }
    // ---- phase A: cf0 rows k0,k0+1 = relu(pf @ Wp + bp); exists head ----
    {
        float4* s_part = (float4*)s_scr;           // [8][64]
        int c = t & 63, g = t >> 6;                // float4-col, f-group of 16
        const float4* W4 = (const float4*)Wp;      // row stride 24576 float4
        size_t base = (size_t)b * 64 + c;
        const float4* pf4 = (const float4*)(pf + g * 16);
        float4 p0 = pf4[0], p1 = pf4[1], p2 = pf4[2], p3 = pf4[3];
        float pv[16] = { p0.x, p0.y, p0.z, p0.w, p1.x, p1.y, p1.z, p1.w,
                         p2.x, p2.y, p2.z, p2.w, p3.x, p3.y, p3.z, p3.w };
        float4 acc = make_float4(0.f, 0.f, 0.f, 0.f);
        #pragma unroll
        for (int q = 0; q < 16; ++q) {
            int f = g * 16 + q;
            float4 w = W4[(size_t)f * 24576 + base];
            float p = pv[q];
            acc.x = fmaf(p, w.x, acc.x);
            acc.y = fmaf(p, w.y, acc.y);
            acc.z = fmaf(p, w.z, acc.z);
            acc.w = fmaf(p, w.w, acc.w);
        }
        s_part[g * 64 + c] = acc;
        __syncthreads();
        if (t < 64) {
            float4 r = s_part[t];
            #pragma unroll
            for (int g2 = 1; g2 < 8; ++g2) {
                float4 p = s_part[g2 * 64 + t];
                r.x += p.x; r.y += p.y; r.z += p.z; r.w += p.w;
            }
            float4 bi = ((const float4*)bp)[b * 64 + t];
            r.x = fmaxf(r.x + bi.x, 0.f);
            r.y = fmaxf(r.y + bi.y, 0.f);
            r.z = fmaxf(r.z + bi.z, 0.f);
            r.w = fmaxf(r.w + bi.w, 0.f);
            int row = t >> 5, h4 = t & 31;
            *(float4*)&s_cf0[row][h4 * 4] = r;
            ((float4*)cf0g)[(size_t)b * 64 + t] = r;
            float4 w = ((const float4*)Wexi)[h4];
            float dot = r.x * w.x + r.y * w.y + r.z * w.z + r.w * w.w;
            dot += __shfl_xor(dot, 16);
            dot += __shfl_xor(dot, 8);
            dot += __shfl_xor(dot, 4);
            dot += __shfl_xor(dot, 2);
            dot += __shfl_xor(dot, 1);
            if (h4 == 0) exO[k0 + row] = dot + bexi[0];
        }
    }
    __syncthreads();
    // ---- phase B: 4 GEMMs (Ael->A_pack(+bel), Bel->BT, A0, B0) ----
    {
        float4* s_p2 = (float4*)s_scr;             // [4 mat][4 q][2 row][32 c]
        int mat = t >> 7, q = (t >> 5) & 3, c = t & 31;
        const float* W = (mat == 0) ? Wel : (mat == 1) ? (Wel + 16384)
                       : (mat == 2) ? Wne : (Wne + 16384);
        float4 a0 = make_float4(0.f, 0.f, 0.f, 0.f);
        float4 a1 = make_float4(0.f, 0.f, 0.f, 0.f);
        #pragma unroll 8
        for (int x = q * 32; x < q * 32 + 32; ++x) {
            float4 w = *(const float4*)&W[x * 128 + c * 4];
            float c0 = s_cf0[0][x], c1 = s_cf0[1][x];
            a0.x = fmaf(c0, w.x, a0.x); a0.y = fmaf(c0, w.y, a0.y);
            a0.z = fmaf(c0, w.z, a0.z); a0.w = fmaf(c0, w.w, a0.w);
            a1.x = fmaf(c1, w.x, a1.x); a1.y = fmaf(c1, w.y, a1.y);
            a1.z = fmaf(c1, w.z, a1.z); a1.w = fmaf(c1, w.w, a1.w);
        }
        s_p2[((mat * 4 + q) * 2 + 0) * 32 + c] = a0;
        s_p2[((mat * 4 + q) * 2 + 1) * 32 + c] = a1;
        __syncthreads();
        if (t < 256) {
            int m2 = t >> 6, row = (t >> 5) & 1, c2 = t & 31;
            float4 r = s_p2[((m2 * 4 + 0) * 2 + row) * 32 + c2];
            #pragma unroll
            for (int q2 = 1; q2 < 4; ++q2) {
                float4 p = s_p2[((m2 * 4 + q2) * 2 + row) * 32 + c2];
                r.x += p.x; r.y += p.y; r.z += p.z; r.w += p.w;
            }
            if (m2 == 0) {
                float4 bl = *(const float4*)&bel[c2 * 4];
                float* ap = A_pack + (k0 >> 2) * 1024 + (k0 & 2) + row;
                ap[(c2 * 4 + 0) * 8] = r.x + bl.x;
                ap[(c2 * 4 + 1) * 8] = r.y + bl.y;
                ap[(c2 * 4 + 2) * 8] = r.z + bl.z;
                ap[(c2 * 4 + 3) * 8] = r.w + bl.w;
            } else if (m2 == 1) {
                BT[(c2 * 4 + 0) * NK + k0 + row] = r.x;
                BT[(c2 * 4 + 1) * NK + k0 + row] = r.y;
                BT[(c2 * 4 + 2) * NK + k0 + row] = r.z;
                BT[(c2 * 4 + 3) * NK + k0 + row] = r.w;
            } else if (m2 == 2) {
                ((float4*)A0)[(size_t)(k0 + row) * 32 + c2] = r;
            } else {
                ((float4*)B0)[(size_t)(k0 + row) * 32 + c2] = r;
            }
        }
    }
}

// K2: edge logits + emask + any_edge. grid(192,3) x 256, tile 4i x 256j.
// Barrier-free: no LDS; exi via uniform loads; flag via ballot + plain store.
__global__ __launch_bounds__(256) void k_edge(const float* __restrict__ A_pack,
    const float* __restrict__ BT, const float* __restrict__ bex,
    const float* __restrict__ exO, float* __restrict__ edge_out,
    unsigned char* __restrict__ mask, unsigned int* __restrict__ flag)
{
    int t = threadIdx.x;
    int i0 = blockIdx.x * 4;
    int j = blockIdx.y * 256 + t;
    float exj = exO[j];                 // issue early
    float exi0 = exO[i0 + 0];           // wave-uniform
    float exi1 = exO[i0 + 1];
    float exi2 = exO[i0 + 2];
    float exi3 = exO[i0 + 3];
    const float* ap = A_pack + blockIdx.x * 1024;   // [128][8], wave-uniform
    const float* btj = BT + j;
    v2f l01[4] = {}, l23[4] = {};
    #pragma unroll 16
    for (int h = 0; h < 128; ++h) {
        float bb = btj[(size_t)h * NK];             // coalesced, L2-resident
        const float* a8 = ap + h * 8;
        float4 av = *(const float4*)a8;             // uniform -> s_load
        float4 wv = *(const float4*)(a8 + 4);       // uniform -> s_load
        v2f e01 = __builtin_elementwise_max((v2f){av.x + bb, av.y + bb}, (v2f){0.f, 0.f});
        v2f e23 = __builtin_elementwise_max((v2f){av.z + bb, av.w + bb}, (v2f){0.f, 0.f});
        l01[0] += e01 * wv.x; l01[1] += e01 * wv.y;
        l01[2] += e01 * wv.z; l01[3] += e01 * wv.w;
        l23[0] += e23 * wv.x; l23[1] += e23 * wv.y;
        l23[2] += e23 * wv.z; l23[3] += e23 * wv.w;
    }
    float b0 = bex[0], b1 = bex[1], b2 = bex[2], b3 = bex[3];
    bool ej = exj > 0.f;
    float4 v0 = make_float4(l01[0].x + b0, l01[1].x + b1, l01[2].x + b2, l01[3].x + b3);
    float4 v1 = make_float4(l01[0].y + b0, l01[1].y + b1, l01[2].y + b2, l01[3].y + b3);
    float4 v2 = make_float4(l23[0].x + b0, l23[1].x + b1, l23[2].x + b2, l23[3].x + b3);
    float4 v3 = make_float4(l23[0].y + b0, l23[1].y + b1, l23[2].y + b2, l23[3].y + b3);
    ((float4*)edge_out)[(size_t)(i0 + 0) * NK + j] = v0;
    ((float4*)edge_out)[(size_t)(i0 + 1) * NK + j] = v1;
    ((float4*)edge_out)[(size_t)(i0 + 2) * NK + j] = v2;
    ((float4*)edge_out)[(size_t)(i0 + 3) * NK + j] = v3;
    bool m0 = ((v0.x > 0.f) | (v0.y > 0.f) | (v0.z > 0.f) | (v0.w > 0.f)) && ej && (exi0 > 0.f);
    bool m1 = ((v1.x > 0.f) | (v1.y > 0.f) | (v1.z > 0.f) | (v1.w > 0.f)) && ej && (exi1 > 0.f);
    bool m2 = ((v2.x > 0.f) | (v2.y > 0.f) | (v2.z > 0.f) | (v2.w > 0.f)) && ej && (exi2 > 0.f);
    bool m3 = ((v3.x > 0.f) | (v3.y > 0.f) | (v3.z > 0.f) | (v3.w > 0.f)) && ej && (exi3 > 0.f);
    mask[(i0 + 0) * NK + j] = m0 ? (unsigned char)1 : (unsigned char)0;
    mask[(i0 + 1) * NK + j] = m1 ? (unsigned char)1 : (unsigned char)0;
    mask[(i0 + 2) * NK + j] = m2 ? (unsigned char)1 : (unsigned char)0;
    mask[(i0 + 3) * NK + j] = m3 ? (unsigned char)1 : (unsigned char)0;
    unsigned long long bal = __ballot((m0 | m1 | m2 | m3) ? 1 : 0);
    if ((t & 63) == 0 && bal) *flag = 1u;   // idempotent plain store
}

// K3: fused masked-max(B0) + combine -> cf1 + GEMM Wne1 -> A1,B1.
// grid 384 x 512; rows 2b,2b+1. float4 scan; s_madd[j][2] LDS staging (R14).
__global__ __launch_bounds__(512) void k_msgA(const float* __restrict__ B0,
    const unsigned char* __restrict__ mask, const float* __restrict__ A0,
    const float* __restrict__ bne, const float* __restrict__ cf0,
    const unsigned int* __restrict__ flag, float* __restrict__ cf1,
    const float* __restrict__ Wne1, float* __restrict__ A1, float* __restrict__ B1)
{
    __shared__ float s_madd[768][2];
    __shared__ float s_red[2][16][32][4];   // 16 KB
    __shared__ float s_cf[2][128];
    int t = threadIdx.x;
    int k0 = blockIdx.x * 2;
    for (int idx = t; idx < 384; idx += 512) {
        int r = idx >= 192 ? 1 : 0, j4 = idx - r * 192;
        uchar4 mm = ((const uchar4*)&mask[(k0 + r) * NK])[j4];
        s_madd[j4 * 4 + 0][r] = mm.x ? 0.f : -1e30f;
        s_madd[j4 * 4 + 1][r] = mm.y ? 0.f : -1e30f;
        s_madd[j4 * 4 + 2][r] = mm.z ? 0.f : -1e30f;
        s_madd[j4 * 4 + 3][r] = mm.w ? 0.f : -1e30f;
    }
    __syncthreads();
    int h4 = t & 31, q = t >> 5;
    {
        v2f M00 = {-1e30f, -1e30f}, M01 = M00, M10 = M00, M11 = M00;
        const float4* B4 = (const float4*)B0;   // row stride 32 float4
        #pragma unroll 16
        for (int jj = 0; jj < 48; ++jj) {
            int j = q * 48 + jj;
            float4 b = B4[(size_t)j * 32 + h4];
            v2f mm2 = *(const v2f*)&s_madd[j][0];
            float m0 = mm2.x, m1 = mm2.y;
            M00 = __builtin_elementwise_max(M00, (v2f){b.x + m0, b.y + m0});
            M01 = __builtin_elementwise_max(M01, (v2f){b.z + m0, b.w + m0});
            M10 = __builtin_elementwise_max(M10, (v2f){b.x + m1, b.y + m1});
            M11 = __builtin_elementwise_max(M11, (v2f){b.z + m1, b.w + m1});
        }
        *(v2f*)&s_red[0][q][h4][0] = M00;
        *(v2f*)&s_red[0][q][h4][2] = M01;
        *(v2f*)&s_red[1][q][h4][0] = M10;
        *(v2f*)&s_red[1][q][h4][2] = M11;
    }
    __syncthreads();
    unsigned int fl = *flag;
    if (t < 256) {
        int kk = t >> 7, hh = t & 127;
        int hq = hh >> 2, c = hh & 3;
        float M = s_red[kk][0][hq][c];
        #pragma unroll
        for (int qq = 1; qq < 16; ++qq) M = fmaxf(M, s_red[kk][qq][hq][c]);
        int g = (k0 + kk) * 128 + hh;
        float v = fl ? fmaxf(A0[g] + bne[hh] + M, 0.f) : cf0[g];
        s_cf[kk][hh] = v;
        cf1[g] = v;
    }
    __syncthreads();
    int h = t & 127, kk = (t >> 7) & 1, half = t >> 8;
    const float* W = Wne1 + half * 16384;
    const float* c = &s_cf[kk][0];
    float acc = 0.f;
    #pragma unroll 8
    for (int r = 0; r < 128; ++r)
        acc = fmaf(c[r], W[r * 128 + h], acc);
    float* D = half ? B1 : A1;
    D[(k0 + kk) * 128 + h] = acc;
}

// K4: fused masked-max(B1) + combine -> cf2 (local) + final heads. grid 384 x 512.
__global__ __launch_bounds__(512) void k_finalf(const float* __restrict__ B1,
    const unsigned char* __restrict__ mask, const float* __restrict__ cf0,
    const float* __restrict__ cf1, const float* __restrict__ A1,
    const float* __restrict__ bne1, const unsigned int* __restrict__ flag,
    const float* __restrict__ Wc, const float* __restrict__ bc,
    const float* __restrict__ Wsem, const float* __restrict__ bsem,
    const float* __restrict__ W2, const float* __restrict__ b2,
    float* __restrict__ out)
{
    __shared__ float s_madd[768][2];
    __shared__ float s_red[2][16][32][4];   // 16 KB
    __shared__ float s_M[2][128];
    __shared__ float s_f[2][384];
    __shared__ float s_h[2][128];
    __shared__ float s_hp[2][128];
    int t = threadIdx.x;
    int k0 = blockIdx.x * 2;
    for (int idx = t; idx < 384; idx += 512) {
        int r = idx >= 192 ? 1 : 0, j4 = idx - r * 192;
        uchar4 mm = ((const uchar4*)&mask[(k0 + r) * NK])[j4];
        s_madd[j4 * 4 + 0][r] = mm.x ? 0.f : -1e30f;
        s_madd[j4 * 4 + 1][r] = mm.y ? 0.f : -1e30f;
        s_madd[j4 * 4 + 2][r] = mm.z ? 0.f : -1e30f;
        s_madd[j4 * 4 + 3][r] = mm.w ? 0.f : -1e30f;
    }
    __syncthreads();
    int h4 = t & 31, q = t >> 5;
    {
        v2f M00 = {-1e30f, -1e30f}, M01 = M00, M10 = M00, M11 = M00;
        const float4* B4 = (const float4*)B1;   // row stride 32 float4
        #pragma unroll 16
        for (int jj = 0; jj < 48; ++jj) {
            int j = q * 48 + jj;
            float4 b = B4[(size_t)j * 32 + h4];
            v2f mm2 = *(const v2f*)&s_madd[j][0];
            float m0 = mm2.x, m1 = mm2.y;
            M00 = __builtin_elementwise_max(M00, (v2f){b.x + m0, b.y + m0});
            M01 = __builtin_elementwise_max(M01, (v2f){b.z + m0, b.w + m0});
            M10 = __builtin_elementwise_max(M10, (v2f){b.x + m1, b.y + m1});
            M11 = __builtin_elementwise_max(M11, (v2f){b.z + m1, b.w + m1});
        }
        *(v2f*)&s_red[0][q][h4][0] = M00;
        *(v2f*)&s_red[0][q][h4][2] = M01;
        *(v2f*)&s_red[1][q][h4][0] = M10;
        *(v2f*)&s_red[1][q][h4][2] = M11;
    }
    __syncthreads();
    if (t < 256) {
        int kk = t >> 7, hh = t & 127;
        int hq = hh >> 2, c = hh & 3;
        float M = s_red[kk][0][hq][c];
        #pragma unroll
        for (int qq = 1; qq < 16; ++qq) M = fmaxf(M, s_red[kk][qq][hq][c]);
        s_M[kk][hh] = M;
    }
    __syncthreads();
    unsigned int fl = *flag;
    for (int idx = t; idx < 768; idx += 512) {
        int kk = idx >= 384 ? 1 : 0;
        int c = idx - kk * 384;
        int row = k0 + kk;
        float v;
        if (c < 128) v = cf0[row * 128 + c];
        else if (c < 256) v = cf1[row * 128 + (c - 128)];
        else {
            int hh = c - 256, g = row * 128 + hh;
            v = fl ? fmaxf(A1[g] + bne1[hh] + s_M[kk][hh], 0.f) : cf1[g];
        }
        s_f[kk][c] = v;
    }
    __syncthreads();
    int h = t & 127, rh = (t >> 7) & 1, kg = t >> 8;
    float acc = 0.f;
    {
        const float* f = &s_f[kg][rh * 192];
        const float* Wcp = Wc + rh * 192 * 128;
        #pragma unroll 8
        for (int r = 0; r < 192; ++r)
            acc = fmaf(f[r], Wcp[r * 128 + h], acc);
    }
    if (rh) s_hp[kg][h] = acc;
    __syncthreads();
    if (!rh) s_h[kg][h] = fmaxf(acc + s_hp[kg][h] + bc[h], 0.f);
    __syncthreads();
    float a2 = 0.f;
    {
        const float* hr = &s_h[kg][rh * 64];
        const float* W2p = W2 + rh * 64 * 128;
        #pragma unroll 8
        for (int r = 0; r < 64; ++r)
            a2 = fmaf(hr[r], W2p[r * 128 + h], a2);
    }
    if (rh) s_hp[kg][h] = a2;
    __syncthreads();
    if (!rh) out[(size_t)(k0 + kg) * 128 + h] = fmaxf(a2 + s_hp[kg][h] + b2[h], 0.f);
    if (t < 114) {
        int kk = t / 57, sidx = t - kk * 57;
        float ss = bsem[sidx];
        const float* hr = &s_h[kk][0];
        #pragma unroll 8
        for (int r = 0; r < 128; ++r)
            ss = fmaf(hr[r], Wsem[r * 57 + sidx], ss);
        out[98304 + (size_t)(k0 + kk) * 57 + sidx] = ss;
    }
}

extern "C" void kernel_launch(void* const* d_in, const int* in_sizes, int n_in,
                              void* d_out, int out_size, void* d_ws, size_t ws_size,
                              hipStream_t stream) {
    const float* pf   = (const float*)d_in[0];
    const float* Wp   = (const float*)d_in[1];
    const float* bp   = (const float*)d_in[2];
    const float* Wexi = (const float*)d_in[3];
    const float* bexi = (const float*)d_in[4];
    const float* Wel  = (const float*)d_in[5];
    const float* bel  = (const float*)d_in[6];
    const float* Wee  = (const float*)d_in[7];
    const float* bee  = (const float*)d_in[8];
    const float* Wne  = (const float*)d_in[9];
    const float* bne  = (const float*)d_in[10];
    const float* Wc   = (const float*)d_in[11];
    const float* bc   = (const float*)d_in[12];
    const float* Wsem = (const float*)d_in[13];
    const float* bsem = (const float*)d_in[14];
    const float* W2   = (const float*)d_in[15];
    const float* b2   = (const float*)d_in[16];
    float* out = (float*)d_out;
    float* ws  = (float*)d_ws;
    const int N = NCF;
    float* cf0    = ws;
    float* cf1    = ws + N;
    float* A_pack = ws + 2 * N;                            // 192*128*8 = 2N floats
    float* BT     = ws + 4 * N;
    float* A0     = ws + 5 * N;
    float* B0     = ws + 6 * N;
    float* A1     = ws + 7 * N;
    float* B1     = ws + 8 * N;
    unsigned char* mask = (unsigned char*)(ws + 9 * N);    // 589824 bytes
    unsigned int* flag  = (unsigned int*)(mask + 589824);

    float* out_ex   = out + 142080;
    float* out_edge = out + 142848;

    k_pd<<<384, 512, 0, stream>>>(pf, Wp, bp, Wexi, bexi, Wel, bel, Wne, Wee,
                                  cf0, out_ex, A_pack, BT, A0, B0, flag);
    k_edge<<<dim3(192, 3), 256, 0, stream>>>(A_pack, BT, bee, out_ex,
                                             out_edge, mask, flag);
    k_msgA<<<384, 512, 0, stream>>>(B0, mask, A0, bne, cf0, flag, cf1,
                                    Wne + 32768, A1, B1);
    k_finalf<<<384, 512, 0, stream>>>(B1, mask, cf0, cf1, A1, bne + 128, flag,
                                      Wc, bc, Wsem, bsem, W2, b2, out);
}